// Round 1
// 668.532 us; speedup vs baseline: 1.0316x; 1.0316x over previous
//
#include <hip/hip_runtime.h>
#include <hip/hip_bf16.h>
#include <stdint.h>

// Problem dims
#define M_DIM 8192
#define K_DIM 7168
#define N_DIM 2112          // 1536 + 512 + 64
#define N_PAD 2112          // 11 * 192 exactly -> no pad columns
#define NQ 1536
#define NKV 512
#define NPE 64
#define NGROUPS 12          // 1536 / 128

// 8-phase GEMM geometry (T2+T3+T4+T5 stack)
#define BM 256
#define BN 192
#define BK 64
#define SPLITK 2
#define KHALF (K_DIM / SPLITK)     // 3584
#define T_TILES (KHALF / BK)       // 56 K-tiles per block
#define MT (M_DIM / BM)            // 32
#define NT (N_DIM / BN)            // 11
#define NWG (MT * NT * SPLITK)     // 704 = 8 * 88

typedef __bf16 bf16x8 __attribute__((ext_vector_type(8)));
typedef float f32x4 __attribute__((ext_vector_type(4)));
typedef unsigned short ushort8 __attribute__((ext_vector_type(8)));

__device__ __forceinline__ unsigned short f32_to_bf16(float f) {
    unsigned int u = __float_as_uint(f);
    u += 0x7fffu + ((u >> 16) & 1u);   // round-to-nearest-even
    return (unsigned short)(u >> 16);
}

__device__ __forceinline__ void gload16(const unsigned short* g, unsigned short* l) {
    __builtin_amdgcn_global_load_lds(
        (const __attribute__((address_space(1))) unsigned int*)g,
        (__attribute__((address_space(3))) unsigned int*)l, 16, 0, 0);
}

// raw barrier: NO implicit vmcnt(0) drain (unlike __syncthreads)
#define SBAR() do { __builtin_amdgcn_sched_barrier(0); \
    asm volatile("" ::: "memory"); \
    __builtin_amdgcn_s_barrier(); \
    __builtin_amdgcn_sched_barrier(0); } while (0)
#define VMCNT(n) asm volatile("s_waitcnt vmcnt(" #n ")" ::: "memory")

// ---------------------------------------------------------------------------
// Kernel 1: A fp32 -> bf16, elementwise, vectorized
// ---------------------------------------------------------------------------
__global__ __launch_bounds__(256) void cvt_a_kernel(
    const float* __restrict__ in, unsigned short* __restrict__ out, int n4)
{
    int idx = blockIdx.x * 256 + threadIdx.x;
    int stride = gridDim.x * 256;
    const float4* in4 = (const float4*)in;
    ushort4* out4 = (ushort4*)out;
    for (int i = idx; i < n4; i += stride) {
        float4 v = in4[i];
        ushort4 o;
        o.x = f32_to_bf16(v.x);
        o.y = f32_to_bf16(v.y);
        o.z = f32_to_bf16(v.z);
        o.w = f32_to_bf16(v.w);
        out4[i] = o;
    }
}

// ---------------------------------------------------------------------------
// Kernel 2: W [K][N] fp32 -> Bt [N_DIM][K] bf16 (tiled transpose + convert)
// ---------------------------------------------------------------------------
__global__ __launch_bounds__(256) void cvt_bt_kernel(
    const float* __restrict__ B, unsigned short* __restrict__ Bt)
{
    __shared__ float tile[64][33];
    const int n0 = blockIdx.x * 32;
    const int k0 = blockIdx.y * 64;
    const int t = threadIdx.x;
    const int tx = t & 31;
    const int ty = t >> 5;
#pragma unroll
    for (int i = 0; i < 8; ++i) {
        int kk = ty + i * 8;
        tile[kk][tx] = B[(size_t)(k0 + kk) * N_DIM + n0 + tx];
    }
    __syncthreads();
    const int n_idx = t >> 3;
    const int k8 = (t & 7) * 8;
    ushort8 o;
#pragma unroll
    for (int j = 0; j < 8; ++j)
        o[j] = f32_to_bf16(tile[k8 + j][n_idx]);
    *reinterpret_cast<ushort8*>(&Bt[(size_t)(n0 + n_idx) * K_DIM + k0 + k8]) = o;
}

// ---------------------------------------------------------------------------
// Kernel 3: bf16 MFMA GEMM, 8-phase counted-vmcnt schedule.
//   Tile 256x192, BK=64, 512 threads (8 waves, 2M x 4N), per-wave 128x48.
//   LDS 112 KiB: A = 4-slot K-half ring (4 x [256][32] bf16, 16 KB/slot),
//                B = 2-buffer K-tile ring (2 x [2][192][32] bf16, 24 KB/buf).
//   st_16x32 swizzle: 16B-chunk ^= (row&8)>>2, applied on both sides
//   (inverse-swizzled global source for global_load_lds; swizzled ds_read).
//   Phase = (K-half, M-half): 12 MFMA per phase, B frags held across M-halves.
//   A-half-tile g+3 / B-tile t+1 prefetched 3-4 phases ahead; boundary fence
//   is vmcnt(2) (counted, never 0 in steady state).
// ---------------------------------------------------------------------------
__global__ __launch_bounds__(512, 2) void gemm8_kernel(
    const unsigned short* __restrict__ A,
    const unsigned short* __restrict__ Bt,
    unsigned short* __restrict__ C)       // [SPLITK][M][N_PAD] bf16
{
    __shared__ unsigned short sm[57344];   // 112 KiB

    const int tid  = threadIdx.x;
    const int lane = tid & 63;
    const int wave = tid >> 6;
    const int wr = wave >> 2;       // 0..1  (M)
    const int wc = wave & 3;        // 0..3  (N)

    // bijective XCD swizzle (NWG = 704 divisible by 8)
    const int bid = blockIdx.x;
    const int swz = (bid & 7) * (NWG / 8) + (bid >> 3);
    const int z   = swz / (MT * NT);
    const int rmn = swz % (MT * NT);
    const int mt  = rmn & 31;        // M fastest
    const int nt  = rmn >> 5;
    const int m0 = mt * BM;
    const int n0 = nt * BN;
    const size_t kbase = (size_t)z * KHALF;

    // ---- staging address precompute (linear LDS dest, inv-swizzled source) ----
    const int lrow  = lane >> 2;                                   // 0..15
    const int csrc8 = ((lane & 3) ^ (((lane >> 5) & 1) << 1)) * 8; // shorts
    const unsigned short* aS0 = A + (size_t)(m0 + wave * 16 + lrow) * K_DIM + kbase + csrc8;
    const unsigned short* aS1 = aS0 + (size_t)128 * K_DIM;
    const int rB1  = (wave < 4) ? (128 + wave * 16 + lrow) : ((wave - 4) * 16 + lrow);
    const int ks1o = (wave >= 4) ? 32 : 0;
    const unsigned short* bS0 = Bt + (size_t)(n0 + wave * 16 + lrow) * K_DIM + kbase + csrc8;
    const unsigned short* bS1 = Bt + (size_t)(n0 + rB1) * K_DIM + kbase + ks1o + csrc8;
    const unsigned short* bS2 = Bt + (size_t)(n0 + 64 + wave * 16 + lrow) * K_DIM + kbase + 32 + csrc8;
    unsigned short* aD = sm + wave * 512;            // + slot*8192 + q*4096 (shorts)
    unsigned short* bD = sm + 32768 + wave * 512;    // + buf*12288 + q*4096

#define STAGE_A(g) do { unsigned short* _d = aD + ((g) & 3) * 8192; \
        gload16(aS0 + (size_t)(g) * 32, _d); \
        gload16(aS1 + (size_t)(g) * 32, _d + 4096); } while (0)
#define STAGE_B(tt) do { unsigned short* _d = bD + ((tt) & 1) * 12288; \
        gload16(bS0 + (size_t)(tt) * 64, _d); \
        gload16(bS1 + (size_t)(tt) * 64, _d + 4096); \
        gload16(bS2 + (size_t)(tt) * 64, _d + 8192); } while (0)

    // ---- LDS read offsets (bytes); same st_16x32 involution as the source ----
    const int rdsw = ((lane >> 4) ^ (((lane >> 3) & 1) << 1)) * 16;
    const int aRd = (wr * 128 + (lane & 15)) * 64 + rdsw;
    const int bRd = 65536 + (wc * 48 + (lane & 15)) * 64 + rdsw;
#define LDSV(off) (*reinterpret_cast<const bf16x8*>(reinterpret_cast<const char*>(sm) + (off)))

    f32x4 acc[8][3];
#pragma unroll
    for (int i = 0; i < 8; ++i)
#pragma unroll
        for (int j = 0; j < 3; ++j) acc[i][j] = (f32x4)0.0f;

#define ROWMFMA(i, av) do { \
        acc[i][0] = __builtin_amdgcn_mfma_f32_16x16x32_bf16(av, b0, acc[i][0], 0, 0, 0); \
        acc[i][1] = __builtin_amdgcn_mfma_f32_16x16x32_bf16(av, b1, acc[i][1], 0, 0, 0); \
        acc[i][2] = __builtin_amdgcn_mfma_f32_16x16x32_bf16(av, b2, acc[i][2], 0, 0, 0); } while (0)

    // ---- prologue: A K-halves 0..2, B tile 0; counted fence (A2 may stay in flight)
    STAGE_A(0);
    STAGE_B(0);
    STAGE_A(1);
    STAGE_A(2);
    VMCNT(2);
    SBAR();

    for (int t = 0; t < T_TILES; ++t) {
        const int aoff = (t & 1) * 32768;   // slot pair {0,1} / {2,3}
        const int boff = (t & 1) * 24576;
        bf16x8 a0, a1, a2, a3, b0, b1, b2;

        // ===== phase 1: ks=0, A frags 0-3, all B ks=0 =====
        b0 = LDSV(bRd + boff);
        b1 = LDSV(bRd + boff + 1024);
        b2 = LDSV(bRd + boff + 2048);
        a0 = LDSV(aRd + aoff);
        a1 = LDSV(aRd + aoff + 1024);
        a2 = LDSV(aRd + aoff + 2048);
        a3 = LDSV(aRd + aoff + 3072);
        if (t < T_TILES - 1) { STAGE_B(t + 1); STAGE_A(2 * t + 3); }
        SBAR();
        __builtin_amdgcn_s_setprio(1);
        ROWMFMA(0, a0); ROWMFMA(1, a1); ROWMFMA(2, a2); ROWMFMA(3, a3);
        __builtin_amdgcn_s_setprio(0);
        SBAR();

        // ===== phase 2: ks=0, A frags 4-7 (B held in regs) =====
        a0 = LDSV(aRd + aoff + 4096);
        a1 = LDSV(aRd + aoff + 5120);
        a2 = LDSV(aRd + aoff + 6144);
        a3 = LDSV(aRd + aoff + 7168);
        SBAR();
        __builtin_amdgcn_s_setprio(1);
        ROWMFMA(4, a0); ROWMFMA(5, a1); ROWMFMA(6, a2); ROWMFMA(7, a3);
        __builtin_amdgcn_s_setprio(0);
        SBAR();

        // ===== phase 3: ks=1, A frags 0-3 =====
        b0 = LDSV(bRd + boff + 12288);
        b1 = LDSV(bRd + boff + 13312);
        b2 = LDSV(bRd + boff + 14336);
        a0 = LDSV(aRd + aoff + 16384);
        a1 = LDSV(aRd + aoff + 17408);
        a2 = LDSV(aRd + aoff + 18432);
        a3 = LDSV(aRd + aoff + 19456);
        if (t < T_TILES - 2) STAGE_A(2 * t + 4);
        SBAR();
        __builtin_amdgcn_s_setprio(1);
        ROWMFMA(0, a0); ROWMFMA(1, a1); ROWMFMA(2, a2); ROWMFMA(3, a3);
        __builtin_amdgcn_s_setprio(0);
        SBAR();

        // ===== phase 4: ks=1, A frags 4-7; counted boundary fence =====
        a0 = LDSV(aRd + aoff + 20480);
        a1 = LDSV(aRd + aoff + 21504);
        a2 = LDSV(aRd + aoff + 22528);
        a3 = LDSV(aRd + aoff + 23552);
        SBAR();
        __builtin_amdgcn_s_setprio(1);
        ROWMFMA(4, a0); ROWMFMA(5, a1); ROWMFMA(6, a2); ROWMFMA(7, a3);
        __builtin_amdgcn_s_setprio(0);
        if (t < T_TILES - 1) {
            if (t < T_TILES - 2) { VMCNT(2); } else { VMCNT(0); }
            SBAR();
        }
    }

    // Epilogue: C/D layout col = lane&15, row = (lane>>4)*4 + v  (m89/m91)
    unsigned short* Cz = C + (size_t)z * M_DIM * N_PAD;
    const int crow = (lane >> 4) * 4;
    const int ccol = lane & 15;
#pragma unroll
    for (int i = 0; i < 8; ++i) {
#pragma unroll
        for (int j = 0; j < 3; ++j) {
            const int gm = m0 + wr * 128 + i * 16 + crow;
            const int gn = n0 + wc * 48 + j * 16 + ccol;
            unsigned short* cp = Cz + (size_t)gm * N_PAD + gn;
#pragma unroll
            for (int v = 0; v < 4; ++v)
                cp[(size_t)v * N_PAD] = f32_to_bf16(acc[i][j][v]);
        }
    }
#undef STAGE_A
#undef STAGE_B
#undef LDSV
#undef ROWMFMA
}

// ---------------------------------------------------------------------------
// Kernel 4: per-row epilogue. Reads both split-K bf16 halves (packed as uint),
// sums in fp32, RMSNorm(q)+group quant, RMSNorm(kv), k_pe.
// One block (256 threads) per row; each quant group == 64 lanes of one wave.
// ---------------------------------------------------------------------------
__global__ __launch_bounds__(256) void epilogue_kernel(
    const unsigned short* __restrict__ C0,
    const unsigned short* __restrict__ C1,
    const float* __restrict__ qw,
    const float* __restrict__ kvw,
    float* __restrict__ out)
{
    const size_t OQ   = 0;
    const size_t OS   = (size_t)M_DIM * NQ;
    const size_t OKV  = OS + (size_t)M_DIM * NGROUPS;
    const size_t OKPE = OKV + (size_t)M_DIM * NKV;

    const int row = blockIdx.x;
    const unsigned int* c0 = (const unsigned int*)(C0 + (size_t)row * N_PAD);
    const unsigned int* c1 = (const unsigned int*)(C1 + (size_t)row * N_PAD);
    const int t = threadIdx.x;
    const int lane = t & 63;
    const int wv = t >> 6;

    __shared__ float red1[4], red2[4];

    float qlo[3], qhi[3];
    float ssq = 0.f;
#pragma unroll
    for (int i = 0; i < 3; ++i) {
        const unsigned int a = c0[t + i * 256];
        const unsigned int b = c1[t + i * 256];
        const float lo = __uint_as_float(a << 16) + __uint_as_float(b << 16);
        const float hi = __uint_as_float(a & 0xffff0000u) + __uint_as_float(b & 0xffff0000u);
        qlo[i] = lo; qhi[i] = hi;
        ssq += lo * lo + hi * hi;
    }
    const unsigned int ka = c0[768 + t];
    const unsigned int kb = c1[768 + t];
    const float klo = __uint_as_float(ka << 16) + __uint_as_float(kb << 16);
    const float khi = __uint_as_float(ka & 0xffff0000u) + __uint_as_float(kb & 0xffff0000u);
    float ssk = klo * klo + khi * khi;

#pragma unroll
    for (int off = 32; off; off >>= 1) {
        ssq += __shfl_down(ssq, off);
        ssk += __shfl_down(ssk, off);
    }
    if (lane == 0) { red1[wv] = ssq; red2[wv] = ssk; }
    __syncthreads();
    ssq = red1[0] + red1[1] + red1[2] + red1[3];
    ssk = red2[0] + red2[1] + red2[2] + red2[3];

    const float rsq = rsqrtf(ssq * (1.0f / NQ) + 1e-6f);
    const float rsk = rsqrtf(ssk * (1.0f / NKV) + 1e-6f);

    const float2* qw2  = (const float2*)qw;
    const float2* kvw2 = (const float2*)kvw;

#pragma unroll
    for (int i = 0; i < 3; ++i) {
        const int colp = t + i * 256;
        const float2 w2 = qw2[colp];
        const float a = qlo[i] * rsq * w2.x;
        const float b = qhi[i] * rsq * w2.y;
        float am = fmaxf(fabsf(a), fabsf(b));
#pragma unroll
        for (int off = 32; off; off >>= 1)
            am = fmaxf(am, __shfl_down(am, off));
        am = __shfl(am, 0);
        const float s = fmaxf(am * (1.0f / 448.0f), 1e-12f);
        if (lane == 0) out[OS + (size_t)row * NGROUPS + i * 4 + wv] = s;
        const float rs = 1.0f / s;
        ((float2*)(out + OQ + (size_t)row * NQ))[colp] = make_float2(a * rs, b * rs);
    }

    const float2 kw2 = kvw2[t];
    ((float2*)(out + OKV + (size_t)row * NKV))[t] =
        make_float2(klo * rsk * kw2.x, khi * rsk * kw2.y);

    if (t < NPE / 2) {
        const unsigned int pa = c0[1024 + t];
        const unsigned int pb = c1[1024 + t];
        ((float2*)(out + OKPE + (size_t)row * NPE))[t] = make_float2(
            __uint_as_float(pa << 16) + __uint_as_float(pb << 16),
            __uint_as_float(pa & 0xffff0000u) + __uint_as_float(pb & 0xffff0000u));
    }
}

// ---------------------------------------------------------------------------
extern "C" void kernel_launch(void* const* d_in, const int* in_sizes, int n_in,
                              void* d_out, int out_size, void* d_ws, size_t ws_size,
                              hipStream_t stream)
{
    const float* hs  = (const float*)d_in[0];   // [8192][7168]
    const float* w   = (const float*)d_in[1];   // [7168][2112]
    const float* qw  = (const float*)d_in[2];   // [1536]
    const float* kvw = (const float*)d_in[3];   // [512]
    float* out = (float*)d_out;

    char* ws = (char*)d_ws;
    const size_t A_BYTES  = (size_t)M_DIM * K_DIM * 2;   // 117,440,512
    const size_t BT_BYTES = (size_t)N_DIM * K_DIM * 2;   //  30,277,632
    unsigned short* Abf = (unsigned short*)ws;
    unsigned short* Bt  = (unsigned short*)(ws + A_BYTES);
    unsigned short* C   = (unsigned short*)(ws + A_BYTES + BT_BYTES);
    unsigned short* C0  = C;
    unsigned short* C1  = C + (size_t)M_DIM * N_PAD;

    // 1) A fp32 -> bf16
    cvt_a_kernel<<<8192, 256, 0, stream>>>(hs, Abf, (M_DIM * K_DIM) / 4);

    // 2) W -> Bt (transpose + convert)
    dim3 gt(N_DIM / 32, K_DIM / 64);
    cvt_bt_kernel<<<gt, 256, 0, stream>>>(w, Bt);

    // 3) GEMM, 8-phase schedule, split-K=2
    gemm8_kernel<<<NWG, 512, 0, stream>>>(Abf, Bt, C);

    // 4) epilogue
    epilogue_kernel<<<M_DIM, 256, 0, stream>>>(C0, C1, qw, kvw, out);
}

// Round 2
// 649.842 us; speedup vs baseline: 1.0613x; 1.0288x over previous
//
#include <hip/hip_runtime.h>
#include <hip/hip_bf16.h>
#include <stdint.h>

// Problem dims
#define M_DIM 8192
#define K_DIM 7168
#define N_DIM 2112          // 1536 + 512 + 64
#define N_PAD 2112          // 11 * 192 exactly -> no pad columns
#define NQ 1536
#define NKV 512
#define NPE 64
#define NGROUPS 12          // 1536 / 128

// GEMM geometry
#define BM 256
#define BN 192
#define BK 64
#define SPLITK 2
#define KHALF (K_DIM / SPLITK)     // 3584
#define T_TILES (KHALF / BK)       // 56 K-tiles per block
#define MT (M_DIM / BM)            // 32
#define NT (N_DIM / BN)            // 11
#define NWG (MT * NT * SPLITK)     // 704 = 8 * 88

typedef __bf16 bf16x8 __attribute__((ext_vector_type(8)));
typedef float f32x4 __attribute__((ext_vector_type(4)));
typedef unsigned short ushort8 __attribute__((ext_vector_type(8)));

__device__ __forceinline__ unsigned short f32_to_bf16(float f) {
    unsigned int u = __float_as_uint(f);
    u += 0x7fffu + ((u >> 16) & 1u);   // round-to-nearest-even
    return (unsigned short)(u >> 16);
}

__device__ __forceinline__ void gload16(const unsigned short* g, unsigned short* l) {
    __builtin_amdgcn_global_load_lds(
        (const __attribute__((address_space(1))) unsigned int*)g,
        (__attribute__((address_space(3))) unsigned int*)l, 16, 0, 0);
}

// raw barrier: NO implicit vmcnt(0) drain (unlike __syncthreads)
#define SBAR() do { __builtin_amdgcn_sched_barrier(0); \
    asm volatile("" ::: "memory"); \
    __builtin_amdgcn_s_barrier(); \
    __builtin_amdgcn_sched_barrier(0); } while (0)
#define VMCNT(n) asm volatile("s_waitcnt vmcnt(" #n ")" ::: "memory")

// ---------------------------------------------------------------------------
// Kernel 1: A fp32 -> bf16, elementwise, vectorized
// ---------------------------------------------------------------------------
__global__ __launch_bounds__(256) void cvt_a_kernel(
    const float* __restrict__ in, unsigned short* __restrict__ out, int n4)
{
    int idx = blockIdx.x * 256 + threadIdx.x;
    int stride = gridDim.x * 256;
    const float4* in4 = (const float4*)in;
    ushort4* out4 = (ushort4*)out;
    for (int i = idx; i < n4; i += stride) {
        float4 v = in4[i];
        ushort4 o;
        o.x = f32_to_bf16(v.x);
        o.y = f32_to_bf16(v.y);
        o.z = f32_to_bf16(v.z);
        o.w = f32_to_bf16(v.w);
        out4[i] = o;
    }
}

// ---------------------------------------------------------------------------
// Kernel 2: W [K][N] fp32 -> Bt [N_DIM][K] bf16 (tiled transpose + convert)
// ---------------------------------------------------------------------------
__global__ __launch_bounds__(256) void cvt_bt_kernel(
    const float* __restrict__ B, unsigned short* __restrict__ Bt)
{
    __shared__ float tile[64][33];
    const int n0 = blockIdx.x * 32;
    const int k0 = blockIdx.y * 64;
    const int t = threadIdx.x;
    const int tx = t & 31;
    const int ty = t >> 5;
#pragma unroll
    for (int i = 0; i < 8; ++i) {
        int kk = ty + i * 8;
        tile[kk][tx] = B[(size_t)(k0 + kk) * N_DIM + n0 + tx];
    }
    __syncthreads();
    const int n_idx = t >> 3;
    const int k8 = (t & 7) * 8;
    ushort8 o;
#pragma unroll
    for (int j = 0; j < 8; ++j)
        o[j] = f32_to_bf16(tile[k8 + j][n_idx]);
    *reinterpret_cast<ushort8*>(&Bt[(size_t)(n0 + n_idx) * K_DIM + k0 + k8]) = o;
}

// ---------------------------------------------------------------------------
// Kernel 3: bf16 MFMA GEMM — 2-barriers-per-K-tile deep-pipelined schedule.
//   Tile 256x192, BK=64, 512 threads (8 waves, 2M x 4N), per-wave 128x48.
//   LDS 112 KiB: A = 4-slot K-half ring (4 x [256][32] bf16, 16 KB/slot),
//                B = 2-buffer K-tile ring (2 x [2][192][32] bf16, 24 KB/buf).
//   st_16x32 swizzle both-sides (inv-swizzled global src, swizzled ds_read).
//   Ring depth makes staging target disjoint buffers from those being read,
//   so only TWO barriers/K-tile are needed:
//     #1 guards STAGE_A(2t+4) overwriting slot (2t)&3   (last read: phase 2)
//     #2 guards next tile's STAGE_B/STAGE_A overwrites  (last read: phase 3/4)
//   Register frag double-buffer (pA/qA/pB/qB): phase p+1's ds_reads issue
//   before phase p's MFMAs -> LDS port drains under the matrix pipe.
//   vmcnt: counted (2) once per tile; full drain only at tile T-2.
// ---------------------------------------------------------------------------
__global__ __launch_bounds__(512, 2) void gemm8_kernel(
    const unsigned short* __restrict__ A,
    const unsigned short* __restrict__ Bt,
    unsigned short* __restrict__ C)       // [SPLITK][M][N_PAD] bf16
{
    __shared__ unsigned short sm[57344];   // 112 KiB

    const int tid  = threadIdx.x;
    const int lane = tid & 63;
    const int wave = tid >> 6;
    const int wr = wave >> 2;       // 0..1  (M)
    const int wc = wave & 3;        // 0..3  (N)

    // bijective XCD swizzle (NWG = 704 divisible by 8)
    const int bid = blockIdx.x;
    const int swz = (bid & 7) * (NWG / 8) + (bid >> 3);
    const int z   = swz / (MT * NT);
    const int rmn = swz % (MT * NT);
    const int mt  = rmn & 31;        // M fastest
    const int nt  = rmn >> 5;
    const int m0 = mt * BM;
    const int n0 = nt * BN;
    const size_t kbase = (size_t)z * KHALF;

    // ---- staging address precompute (linear LDS dest, inv-swizzled source) ----
    const int lrow  = lane >> 2;                                   // 0..15
    const int csrc8 = ((lane & 3) ^ (((lane >> 5) & 1) << 1)) * 8; // shorts
    const unsigned short* aS0 = A + (size_t)(m0 + wave * 16 + lrow) * K_DIM + kbase + csrc8;
    const unsigned short* aS1 = aS0 + (size_t)128 * K_DIM;
    const int rB1  = (wave < 4) ? (128 + wave * 16 + lrow) : ((wave - 4) * 16 + lrow);
    const int ks1o = (wave >= 4) ? 32 : 0;
    const unsigned short* bS0 = Bt + (size_t)(n0 + wave * 16 + lrow) * K_DIM + kbase + csrc8;
    const unsigned short* bS1 = Bt + (size_t)(n0 + rB1) * K_DIM + kbase + ks1o + csrc8;
    const unsigned short* bS2 = Bt + (size_t)(n0 + 64 + wave * 16 + lrow) * K_DIM + kbase + 32 + csrc8;
    unsigned short* aD = sm + wave * 512;            // + slot*8192 + q*4096 (shorts)
    unsigned short* bD = sm + 32768 + wave * 512;    // + buf*12288 + q*4096

#define STAGE_A(g) do { unsigned short* _d = aD + ((g) & 3) * 8192; \
        gload16(aS0 + (size_t)(g) * 32, _d); \
        gload16(aS1 + (size_t)(g) * 32, _d + 4096); } while (0)
#define STAGE_B(tt) do { unsigned short* _d = bD + ((tt) & 1) * 12288; \
        gload16(bS0 + (size_t)(tt) * 64, _d); \
        gload16(bS1 + (size_t)(tt) * 64, _d + 4096); \
        gload16(bS2 + (size_t)(tt) * 64, _d + 8192); } while (0)

    // ---- LDS read offsets (bytes); same st_16x32 involution as the source ----
    const int rdsw = ((lane >> 4) ^ (((lane >> 3) & 1) << 1)) * 16;
    const int aRd = (wr * 128 + (lane & 15)) * 64 + rdsw;
    const int bRd = 65536 + (wc * 48 + (lane & 15)) * 64 + rdsw;
#define LDSV(off) (*reinterpret_cast<const bf16x8*>(reinterpret_cast<const char*>(sm) + (off)))

    f32x4 acc[8][3];
#pragma unroll
    for (int i = 0; i < 8; ++i)
#pragma unroll
        for (int j = 0; j < 3; ++j) acc[i][j] = (f32x4)0.0f;

#define MF(i, AV, B0_, B1_, B2_) do { \
        acc[i][0] = __builtin_amdgcn_mfma_f32_16x16x32_bf16(AV, B0_, acc[i][0], 0, 0, 0); \
        acc[i][1] = __builtin_amdgcn_mfma_f32_16x16x32_bf16(AV, B1_, acc[i][1], 0, 0, 0); \
        acc[i][2] = __builtin_amdgcn_mfma_f32_16x16x32_bf16(AV, B2_, acc[i][2], 0, 0, 0); } while (0)

    // ---- prologue: A K-halves 0..2, B tile 0; counted fence (A2 stays in flight)
    STAGE_A(0);
    STAGE_B(0);
    STAGE_A(1);
    STAGE_A(2);
    VMCNT(2);
    SBAR();

    for (int t = 0; t < T_TILES; ++t) {
        const int aoff = (t & 1) * 32768;   // bytes: slot pair {0,1} / {2,3}
        const int boff = (t & 1) * 24576;
        bf16x8 pA0, pA1, pA2, pA3, qA0, qA1, qA2, qA3;
        bf16x8 pB0, pB1, pB2, qB0, qB1, qB2;

        // ---- S1: phase-1 frags (B ks=0, A half-0 frags 0-3) ----
        pB0 = LDSV(bRd + boff);
        pB1 = LDSV(bRd + boff + 1024);
        pB2 = LDSV(bRd + boff + 2048);
        pA0 = LDSV(aRd + aoff);
        pA1 = LDSV(aRd + aoff + 1024);
        pA2 = LDSV(aRd + aoff + 2048);
        pA3 = LDSV(aRd + aoff + 3072);
        // ---- S2: phase-2 A frags (half-0 frags 4-7) ----
        qA0 = LDSV(aRd + aoff + 4096);
        qA1 = LDSV(aRd + aoff + 5120);
        qA2 = LDSV(aRd + aoff + 6144);
        qA3 = LDSV(aRd + aoff + 7168);
        // ---- G1: prefetch B(t+1) and A half 2t+3 ----
        if (t < T_TILES - 1) { STAGE_B(t + 1); STAGE_A(2 * t + 3); }

        // ---- MFMA phase 1 (acc rows 0-3, ks=0) ----
        __builtin_amdgcn_s_setprio(1);
        MF(0, pA0, pB0, pB1, pB2);
        MF(1, pA1, pB0, pB1, pB2);
        MF(2, pA2, pB0, pB1, pB2);
        MF(3, pA3, pB0, pB1, pB2);
        __builtin_amdgcn_s_setprio(0);

        // ---- S3: phase-3 frags (B ks=1, A half-1 frags 0-3) ----
        qB0 = LDSV(bRd + boff + 12288);
        qB1 = LDSV(bRd + boff + 13312);
        qB2 = LDSV(bRd + boff + 14336);
        pA0 = LDSV(aRd + aoff + 16384);
        pA1 = LDSV(aRd + aoff + 17408);
        pA2 = LDSV(aRd + aoff + 18432);
        pA3 = LDSV(aRd + aoff + 19456);

        // ---- MFMA phase 2 (acc rows 4-7, ks=0) ----
        __builtin_amdgcn_s_setprio(1);
        MF(4, qA0, pB0, pB1, pB2);
        MF(5, qA1, pB0, pB1, pB2);
        MF(6, qA2, pB0, pB1, pB2);
        MF(7, qA3, pB0, pB1, pB2);
        __builtin_amdgcn_s_setprio(0);

        // ==== barrier #1: all waves' phase-2 reads of slot (2t)&3 complete ====
        SBAR();
        // ---- G2: prefetch A half 2t+4 (overwrites slot (2t)&3) ----
        if (t < T_TILES - 2) STAGE_A(2 * t + 4);

        // ---- S4: phase-4 A frags (half-1 frags 4-7) ----
        qA0 = LDSV(aRd + aoff + 20480);
        qA1 = LDSV(aRd + aoff + 21504);
        qA2 = LDSV(aRd + aoff + 22528);
        qA3 = LDSV(aRd + aoff + 23552);

        // ---- MFMA phase 3 (acc rows 0-3, ks=1) ----
        __builtin_amdgcn_s_setprio(1);
        MF(0, pA0, qB0, qB1, qB2);
        MF(1, pA1, qB0, qB1, qB2);
        MF(2, pA2, qB0, qB1, qB2);
        MF(3, pA3, qB0, qB1, qB2);
        // ---- MFMA phase 4 (acc rows 4-7, ks=1) ----
        MF(4, qA0, qB0, qB1, qB2);
        MF(5, qA1, qB0, qB1, qB2);
        MF(6, qA2, qB0, qB1, qB2);
        MF(7, qA3, qB0, qB1, qB2);
        __builtin_amdgcn_s_setprio(0);

        // ==== tile boundary: counted vmem fence + barrier #2 ====
        if (t < T_TILES - 1) {
            if (t < T_TILES - 2) { VMCNT(2); } else { VMCNT(0); }
            SBAR();
        }
    }

    // Epilogue: C/D layout col = lane&15, row = (lane>>4)*4 + v  (m89/m91)
    unsigned short* Cz = C + (size_t)z * M_DIM * N_PAD;
    const int crow = (lane >> 4) * 4;
    const int ccol = lane & 15;
#pragma unroll
    for (int i = 0; i < 8; ++i) {
#pragma unroll
        for (int j = 0; j < 3; ++j) {
            const int gm = m0 + wr * 128 + i * 16 + crow;
            const int gn = n0 + wc * 48 + j * 16 + ccol;
            unsigned short* cp = Cz + (size_t)gm * N_PAD + gn;
#pragma unroll
            for (int v = 0; v < 4; ++v)
                cp[(size_t)v * N_PAD] = f32_to_bf16(acc[i][j][v]);
        }
    }
#undef STAGE_A
#undef STAGE_B
#undef LDSV
#undef MF
}

// ---------------------------------------------------------------------------
// Kernel 4: per-row epilogue. Reads both split-K bf16 halves (packed as uint),
// sums in fp32, RMSNorm(q)+group quant, RMSNorm(kv), k_pe.
// ---------------------------------------------------------------------------
__global__ __launch_bounds__(256) void epilogue_kernel(
    const unsigned short* __restrict__ C0,
    const unsigned short* __restrict__ C1,
    const float* __restrict__ qw,
    const float* __restrict__ kvw,
    float* __restrict__ out)
{
    const size_t OQ   = 0;
    const size_t OS   = (size_t)M_DIM * NQ;
    const size_t OKV  = OS + (size_t)M_DIM * NGROUPS;
    const size_t OKPE = OKV + (size_t)M_DIM * NKV;

    const int row = blockIdx.x;
    const unsigned int* c0 = (const unsigned int*)(C0 + (size_t)row * N_PAD);
    const unsigned int* c1 = (const unsigned int*)(C1 + (size_t)row * N_PAD);
    const int t = threadIdx.x;
    const int lane = t & 63;
    const int wv = t >> 6;

    __shared__ float red1[4], red2[4];

    float qlo[3], qhi[3];
    float ssq = 0.f;
#pragma unroll
    for (int i = 0; i < 3; ++i) {
        const unsigned int a = c0[t + i * 256];
        const unsigned int b = c1[t + i * 256];
        const float lo = __uint_as_float(a << 16) + __uint_as_float(b << 16);
        const float hi = __uint_as_float(a & 0xffff0000u) + __uint_as_float(b & 0xffff0000u);
        qlo[i] = lo; qhi[i] = hi;
        ssq += lo * lo + hi * hi;
    }
    const unsigned int ka = c0[768 + t];
    const unsigned int kb = c1[768 + t];
    const float klo = __uint_as_float(ka << 16) + __uint_as_float(kb << 16);
    const float khi = __uint_as_float(ka & 0xffff0000u) + __uint_as_float(kb & 0xffff0000u);
    float ssk = klo * klo + khi * khi;

#pragma unroll
    for (int off = 32; off; off >>= 1) {
        ssq += __shfl_down(ssq, off);
        ssk += __shfl_down(ssk, off);
    }
    if (lane == 0) { red1[wv] = ssq; red2[wv] = ssk; }
    __syncthreads();
    ssq = red1[0] + red1[1] + red1[2] + red1[3];
    ssk = red2[0] + red2[1] + red2[2] + red2[3];

    const float rsq = rsqrtf(ssq * (1.0f / NQ) + 1e-6f);
    const float rsk = rsqrtf(ssk * (1.0f / NKV) + 1e-6f);

    const float2* qw2  = (const float2*)qw;
    const float2* kvw2 = (const float2*)kvw;

#pragma unroll
    for (int i = 0; i < 3; ++i) {
        const int colp = t + i * 256;
        const float2 w2 = qw2[colp];
        const float a = qlo[i] * rsq * w2.x;
        const float b = qhi[i] * rsq * w2.y;
        float am = fmaxf(fabsf(a), fabsf(b));
#pragma unroll
        for (int off = 32; off; off >>= 1)
            am = fmaxf(am, __shfl_down(am, off));
        am = __shfl(am, 0);
        const float s = fmaxf(am * (1.0f / 448.0f), 1e-12f);
        if (lane == 0) out[OS + (size_t)row * NGROUPS + i * 4 + wv] = s;
        const float rs = 1.0f / s;
        ((float2*)(out + OQ + (size_t)row * NQ))[colp] = make_float2(a * rs, b * rs);
    }

    const float2 kw2 = kvw2[t];
    ((float2*)(out + OKV + (size_t)row * NKV))[t] =
        make_float2(klo * rsk * kw2.x, khi * rsk * kw2.y);

    if (t < NPE / 2) {
        const unsigned int pa = c0[1024 + t];
        const unsigned int pb = c1[1024 + t];
        ((float2*)(out + OKPE + (size_t)row * NPE))[t] = make_float2(
            __uint_as_float(pa << 16) + __uint_as_float(pb << 16),
            __uint_as_float(pa & 0xffff0000u) + __uint_as_float(pb & 0xffff0000u));
    }
}

// ---------------------------------------------------------------------------
extern "C" void kernel_launch(void* const* d_in, const int* in_sizes, int n_in,
                              void* d_out, int out_size, void* d_ws, size_t ws_size,
                              hipStream_t stream)
{
    const float* hs  = (const float*)d_in[0];   // [8192][7168]
    const float* w   = (const float*)d_in[1];   // [7168][2112]
    const float* qw  = (const float*)d_in[2];   // [1536]
    const float* kvw = (const float*)d_in[3];   // [512]
    float* out = (float*)d_out;

    char* ws = (char*)d_ws;
    const size_t A_BYTES  = (size_t)M_DIM * K_DIM * 2;   // 117,440,512
    const size_t BT_BYTES = (size_t)N_DIM * K_DIM * 2;   //  30,277,632
    unsigned short* Abf = (unsigned short*)ws;
    unsigned short* Bt  = (unsigned short*)(ws + A_BYTES);
    unsigned short* C   = (unsigned short*)(ws + A_BYTES + BT_BYTES);
    unsigned short* C0  = C;
    unsigned short* C1  = C + (size_t)M_DIM * N_PAD;

    // 1) A fp32 -> bf16
    cvt_a_kernel<<<8192, 256, 0, stream>>>(hs, Abf, (M_DIM * K_DIM) / 4);

    // 2) W -> Bt (transpose + convert)
    dim3 gt(N_DIM / 32, K_DIM / 64);
    cvt_bt_kernel<<<gt, 256, 0, stream>>>(w, Bt);

    // 3) GEMM, 2-barrier deep-pipelined schedule, split-K=2
    gemm8_kernel<<<NWG, 512, 0, stream>>>(Abf, Bt, C);

    // 4) epilogue
    epilogue_kernel<<<M_DIM, 256, 0, stream>>>(C0, C1, qw, kvw, out);
}